// Round 1
// baseline (98.877 us; speedup 1.0000x reference)
//
#include <hip/hip_runtime.h>
#include <math.h>

__global__ __launch_bounds__(128) void convpolicy_kernel(
    const float* __restrict__ x,
    const float* __restrict__ w1, const float* __restrict__ b1,
    const float* __restrict__ w2, const float* __restrict__ b2,
    const float* __restrict__ w3, const float* __restrict__ b3,
    const float* __restrict__ e1w, const float* __restrict__ e1b,
    const float* __restrict__ e2w, const float* __restrict__ e2b,
    const float* __restrict__ d1w, const float* __restrict__ d1b,
    const float* __restrict__ d2w, const float* __restrict__ d2b,
    const float* __restrict__ d3w, const float* __restrict__ d3b,
    const float* __restrict__ d4w, const float* __restrict__ d4b,
    float* __restrict__ out)
{
    __shared__ float jcat[180];   // (12,15)
    __shared__ float fmc1[78];    // (6,13)
    __shared__ float dsb[30];     // (6,5)
    __shared__ float fmc2[12];    // (4,3)
    __shared__ float embin[6];    // (6,1)
    __shared__ float emb1[4];
    __shared__ float emb2[4];
    __shared__ float dc1[12];     // (4,3)
    __shared__ float dc2[10];     // (2,5)
    __shared__ float usb[26];     // (2,13)
    __shared__ float dc3[30];     // (2,15)
    __shared__ float psi_s;

    const int tid = threadIdx.x;

    // ---- stage A: build jcat (12,15) and psi ----
    for (int idx = tid; idx < 180; idx += 128) {
        float v;
        if (idx < 90) {
            v = (idx < 2) ? 0.f : x[5 + idx];          // jl: x[7 + f - 2]
        } else {
            int f = idx - 90;
            v = (f < 2) ? 0.f : x[99 + f];             // jdl: x[101 + f - 2]
        }
        jcat[idx] = v;
    }
    if (tid == 0) {
        float qw = x[3], qx = x[4], qy = x[5], qz = x[6];
        psi_s = atan2f(qz, qw) - atan2f(-qx, qy);
    }
    __syncthreads();

    // ---- stage B: conv1 (6,12,3): (12,15) -> (6,13), tanh ----
    if (tid < 78) {
        int o = tid / 13, i = tid % 13;
        float acc = b1[o];
        const float* wr = w1 + o * 36;
        #pragma unroll
        for (int c = 0; c < 12; ++c)
            #pragma unroll
            for (int k = 0; k < 3; ++k)
                acc += wr[c * 3 + k] * jcat[c * 15 + i + k];
        fmc1[tid] = tanhf(acc);
    }
    __syncthreads();

    // ---- stage C: adaptive avg pool 13 -> 5 ----
    if (tid < 30) {
        int c = tid / 5, o = tid % 5;
        int s = (o * 13) / 5;
        int e = ((o + 1) * 13 + 4) / 5;   // ceil
        float acc = 0.f;
        for (int l = s; l < e; ++l) acc += fmc1[c * 13 + l];
        dsb[tid] = acc / (float)(e - s);
    }
    __syncthreads();

    // ---- stage D: conv2 (4,6,3): (6,5) -> (4,3), tanh ----
    if (tid < 12) {
        int o = tid / 3, i = tid % 3;
        float acc = b2[o];
        const float* wr = w2 + o * 18;
        #pragma unroll
        for (int c = 0; c < 6; ++c)
            #pragma unroll
            for (int k = 0; k < 3; ++k)
                acc += wr[c * 3 + k] * dsb[c * 5 + i + k];
        fmc2[tid] = tanhf(acc);
    }
    __syncthreads();

    // ---- stage E: conv3 (4,4,3): (4,3) -> (4,1), tanh; build embin ----
    if (tid < 4) {
        float acc = b3[tid];
        const float* wr = w3 + tid * 12;
        #pragma unroll
        for (int c = 0; c < 4; ++c)
            #pragma unroll
            for (int k = 0; k < 3; ++k)
                acc += wr[c * 3 + k] * fmc2[c * 3 + k];
        embin[tid] = tanhf(acc);   // fm_links == fm_c3 (mean over L=1)
    } else if (tid == 4) {
        embin[4] = psi_s;
    } else if (tid == 5) {
        embin[5] = x[100];
    }
    __syncthreads();

    // ---- stage F: emb1 (4,6,1), tanh ----
    if (tid < 4) {
        float acc = e1b[tid];
        #pragma unroll
        for (int c = 0; c < 6; ++c) acc += e1w[tid * 6 + c] * embin[c];
        emb1[tid] = tanhf(acc);
    }
    __syncthreads();

    // ---- stage G: emb2 (4,4,1), tanh ----
    if (tid < 4) {
        float acc = e2b[tid];
        #pragma unroll
        for (int c = 0; c < 4; ++c) acc += e2w[tid * 4 + c] * emb1[c];
        emb2[tid] = tanhf(acc);
    }
    __syncthreads();

    // ---- stage H: dec1 convT (4,4,3): (4,1) -> (4,3), tanh ----
    // y[o][t] = b + sum_c w[c][o][t] * emb2[c]
    if (tid < 12) {
        int o = tid / 3, t = tid % 3;
        float acc = d1b[o];
        #pragma unroll
        for (int c = 0; c < 4; ++c)
            acc += d1w[c * 12 + o * 3 + t] * emb2[c];
        dc1[tid] = tanhf(acc);
    }
    __syncthreads();

    // ---- stage I: dec2 convT (4,2,3): (4,3) -> (2,5), tanh ----
    // y[o][t] = b + sum_c sum_{i in [t-2,t] cap [0,3)} w[c][o][t-i] * dc1[c][i]
    if (tid < 10) {
        int o = tid / 5, t = tid % 5;
        float acc = d2b[o];
        int ilo = (t - 2 > 0) ? t - 2 : 0;
        int ihi = (t < 2) ? t : 2;
        for (int c = 0; c < 4; ++c)
            for (int i = ilo; i <= ihi; ++i)
                acc += d2w[c * 6 + o * 3 + (t - i)] * dc1[c * 3 + i];
        dc2[tid] = tanhf(acc);
    }
    __syncthreads();

    // ---- stage J: upsample 5 -> 13 (nearest, floor(l*5/13)) ----
    if (tid < 26) {
        int c = tid / 13, l = tid % 13;
        usb[tid] = dc2[c * 5 + (l * 5) / 13];
    }
    __syncthreads();

    // ---- stage K: dec3 convT (2,2,3): (2,13) -> (2,15), tanh ----
    if (tid < 30) {
        int o = tid / 15, t = tid % 15;
        float acc = d3b[o];
        int ilo = (t - 2 > 0) ? t - 2 : 0;
        int ihi = (t < 12) ? t : 12;
        for (int c = 0; c < 2; ++c)
            for (int i = ilo; i <= ihi; ++i)
                acc += d3w[c * 6 + o * 3 + (t - i)] * usb[c * 13 + i];
        dc3[tid] = tanhf(acc);
    }
    __syncthreads();

    // ---- stage L: dec4 convT (14,6,3) pad=1: (14,15) -> (6,15); out = flat[2:] ----
    // y[o][t] = b + sum_c sum_{i in [t-1,t+1] cap [0,15)} w[c][o][t-i+1] * in14[c][i]
    if (tid < 88) {
        int g = tid + 2;
        int o = g / 15, t = g % 15;
        float acc = d4b[o];
        int ilo = (t - 1 > 0) ? t - 1 : 0;
        int ihi = (t + 1 < 14) ? t + 1 : 14;
        for (int c = 0; c < 14; ++c) {
            const float* src = (c < 2) ? (dc3 + c * 15) : (jcat + (c - 2) * 15);
            for (int i = ilo; i <= ihi; ++i)
                acc += d4w[c * 18 + o * 3 + (t - i + 1)] * src[i];
        }
        out[tid] = acc;
    }
}

extern "C" void kernel_launch(void* const* d_in, const int* in_sizes, int n_in,
                              void* d_out, int out_size, void* d_ws, size_t ws_size,
                              hipStream_t stream) {
    const float* x   = (const float*)d_in[0];
    const float* w1  = (const float*)d_in[1];
    const float* b1  = (const float*)d_in[2];
    const float* w2  = (const float*)d_in[3];
    const float* b2  = (const float*)d_in[4];
    const float* w3  = (const float*)d_in[5];
    const float* b3  = (const float*)d_in[6];
    const float* e1w = (const float*)d_in[7];
    const float* e1b = (const float*)d_in[8];
    const float* e2w = (const float*)d_in[9];
    const float* e2b = (const float*)d_in[10];
    const float* d1w = (const float*)d_in[11];
    const float* d1b = (const float*)d_in[12];
    const float* d2w = (const float*)d_in[13];
    const float* d2b = (const float*)d_in[14];
    const float* d3w = (const float*)d_in[15];
    const float* d3b = (const float*)d_in[16];
    const float* d4w = (const float*)d_in[17];
    const float* d4b = (const float*)d_in[18];
    float* out = (float*)d_out;

    convpolicy_kernel<<<1, 128, 0, stream>>>(
        x, w1, b1, w2, b2, w3, b3, e1w, e1b, e2w, e2b,
        d1w, d1b, d2w, d2b, d3w, d3b, d4w, d4b, out);
}

// Round 2
// 94.197 us; speedup vs baseline: 1.0497x; 1.0497x over previous
//
#include <hip/hip_runtime.h>
#include <math.h>

// Packed LDS weight-buffer offsets (floats):
//  w1:0(216) b1:216(6) w2:222(72) b2:294(4) w3:298(48) b3:346(4)
//  e1w:350(24) e1b:374(4) e2w:378(16) e2b:394(4)
//  d1w:398(48) d1b:446(4) d2w:450(24) d2b:474(2) d3w:476(12) d3b:488(2)
//  d4w:490(252) d4b:742(6)   total 748

__device__ __forceinline__ float tanh_fast(float v) {
    v = fminf(15.f, fmaxf(-15.f, v));
    float e = __expf(2.f * v);
    return (e - 1.f) * __builtin_amdgcn_rcpf(e + 1.f);
}

__global__ __launch_bounds__(256) void convpolicy_kernel(
    const float* __restrict__ x,
    const float* __restrict__ w1, const float* __restrict__ b1,
    const float* __restrict__ w2, const float* __restrict__ b2,
    const float* __restrict__ w3, const float* __restrict__ b3,
    const float* __restrict__ e1w, const float* __restrict__ e1b,
    const float* __restrict__ e2w, const float* __restrict__ e2b,
    const float* __restrict__ d1w, const float* __restrict__ d1b,
    const float* __restrict__ d2w, const float* __restrict__ d2b,
    const float* __restrict__ d3w, const float* __restrict__ d3b,
    const float* __restrict__ d4w, const float* __restrict__ d4b,
    float* __restrict__ out)
{
    __shared__ float wbuf[748];
    __shared__ float jcat[180];   // (12,15)
    __shared__ float fmc1[78];    // (6,13)
    __shared__ float dsb[30];     // (6,5)
    __shared__ float fmc2[12];    // (4,3)
    __shared__ float embin[6];
    __shared__ float emb1[4];
    __shared__ float emb2[4];
    __shared__ float dc1[12];     // (4,3)
    __shared__ float dc2[10];     // (2,5)
    __shared__ float usb[26];     // (2,13)
    __shared__ float dc3[30];     // (2,15)
    __shared__ float psi_s, xv100;

    const int tid = threadIdx.x;

    // ---- prefetch: ALL global loads issued before the first barrier ----
    // (a) packed weights -> wbuf via branchless segment select
    #pragma unroll
    for (int r = 0; r < 3; ++r) {
        int g = tid + r * 256;
        if (g < 748) {
            const float* p = w1; int o = g;
            #define SEG_STEP(S, P) if (g >= S) { p = P; o = g - S; }
            SEG_STEP(216, b1)  SEG_STEP(222, w2)  SEG_STEP(294, b2)
            SEG_STEP(298, w3)  SEG_STEP(346, b3)  SEG_STEP(350, e1w)
            SEG_STEP(374, e1b) SEG_STEP(378, e2w) SEG_STEP(394, e2b)
            SEG_STEP(398, d1w) SEG_STEP(446, d1b) SEG_STEP(450, d2w)
            SEG_STEP(474, d2b) SEG_STEP(476, d3w) SEG_STEP(488, d3b)
            SEG_STEP(490, d4w) SEG_STEP(742, d4b)
            #undef SEG_STEP
            wbuf[g] = p[o];
        }
    }
    // (b) jcat (12,15) straight from global x, concurrent with (a)
    if (tid < 180) {
        float v;
        if (tid < 90) {
            v = (tid < 2) ? 0.f : x[5 + tid];          // jl
        } else {
            int f = tid - 90;
            v = (f < 2) ? 0.f : x[99 + f];             // jdl
        }
        jcat[tid] = v;
    } else if (tid == 180) {
        float qw = x[3], qx = x[4], qy = x[5], qz = x[6];
        psi_s = atan2f(qz, qw) - atan2f(-qx, qy);
    } else if (tid == 181) {
        xv100 = x[100];
    }
    __syncthreads();

    const float* W1  = wbuf;       const float* B1  = wbuf + 216;
    const float* W2  = wbuf + 222; const float* B2  = wbuf + 294;
    const float* W3  = wbuf + 298; const float* B3  = wbuf + 346;
    const float* E1W = wbuf + 350; const float* E1B = wbuf + 374;
    const float* E2W = wbuf + 378; const float* E2B = wbuf + 394;
    const float* D1W = wbuf + 398; const float* D1B = wbuf + 446;
    const float* D2W = wbuf + 450; const float* D2B = wbuf + 474;
    const float* D3W = wbuf + 476; const float* D3B = wbuf + 488;
    const float* D4W = wbuf + 490; const float* D4B = wbuf + 742;

    // ---- conv1 (6,12,3): (12,15) -> (6,13), tanh ----
    if (tid < 78) {
        int o = tid / 13, i = tid % 13;
        float acc = B1[o];
        const float* wr = W1 + o * 36;
        #pragma unroll
        for (int c = 0; c < 12; ++c)
            #pragma unroll
            for (int k = 0; k < 3; ++k)
                acc += wr[c * 3 + k] * jcat[c * 15 + i + k];
        fmc1[tid] = tanh_fast(acc);
    }
    __syncthreads();

    // ---- adaptive avg pool 13 -> 5 ----
    if (tid < 30) {
        int c = tid / 5, o = tid % 5;
        int s = (o * 13) / 5;
        int e = ((o + 1) * 13 + 4) / 5;
        float acc = 0.f;
        for (int l = s; l < e; ++l) acc += fmc1[c * 13 + l];
        dsb[tid] = acc / (float)(e - s);
    }
    __syncthreads();

    // ---- conv2 (4,6,3): (6,5) -> (4,3), tanh ----
    if (tid < 12) {
        int o = tid / 3, i = tid % 3;
        float acc = B2[o];
        const float* wr = W2 + o * 18;
        #pragma unroll
        for (int c = 0; c < 6; ++c)
            #pragma unroll
            for (int k = 0; k < 3; ++k)
                acc += wr[c * 3 + k] * dsb[c * 5 + i + k];
        fmc2[tid] = tanh_fast(acc);
    }
    __syncthreads();

    // ---- conv3 (4,4,3): (4,3) -> (4,1), tanh; build embin ----
    if (tid < 4) {
        float acc = B3[tid];
        const float* wr = W3 + tid * 12;
        #pragma unroll
        for (int c = 0; c < 4; ++c)
            #pragma unroll
            for (int k = 0; k < 3; ++k)
                acc += wr[c * 3 + k] * fmc2[c * 3 + k];
        embin[tid] = tanh_fast(acc);
    } else if (tid == 4) {
        embin[4] = psi_s;
    } else if (tid == 5) {
        embin[5] = xv100;
    }
    __syncthreads();

    // ---- emb1 (4,6,1), tanh ----
    if (tid < 4) {
        float acc = E1B[tid];
        #pragma unroll
        for (int c = 0; c < 6; ++c) acc += E1W[tid * 6 + c] * embin[c];
        emb1[tid] = tanh_fast(acc);
    }
    __syncthreads();

    // ---- emb2 (4,4,1), tanh ----
    if (tid < 4) {
        float acc = E2B[tid];
        #pragma unroll
        for (int c = 0; c < 4; ++c) acc += E2W[tid * 4 + c] * emb1[c];
        emb2[tid] = tanh_fast(acc);
    }
    __syncthreads();

    // ---- dec1 convT (4,4,3): (4,1) -> (4,3), tanh ----
    if (tid < 12) {
        int o = tid / 3, t = tid % 3;
        float acc = D1B[o];
        #pragma unroll
        for (int c = 0; c < 4; ++c)
            acc += D1W[c * 12 + o * 3 + t] * emb2[c];
        dc1[tid] = tanh_fast(acc);
    }
    __syncthreads();

    // ---- dec2 convT (4,2,3): (4,3) -> (2,5), tanh ----
    if (tid < 10) {
        int o = tid / 5, t = tid % 5;
        float acc = D2B[o];
        int ilo = (t - 2 > 0) ? t - 2 : 0;
        int ihi = (t < 2) ? t : 2;
        for (int c = 0; c < 4; ++c)
            for (int i = ilo; i <= ihi; ++i)
                acc += D2W[c * 6 + o * 3 + (t - i)] * dc1[c * 3 + i];
        dc2[tid] = tanh_fast(acc);
    }
    __syncthreads();

    // ---- upsample 5 -> 13 ----
    if (tid < 26) {
        int c = tid / 13, l = tid % 13;
        usb[tid] = dc2[c * 5 + (l * 5) / 13];
    }
    __syncthreads();

    // ---- dec3 convT (2,2,3): (2,13) -> (2,15), tanh ----
    if (tid < 30) {
        int o = tid / 15, t = tid % 15;
        float acc = D3B[o];
        int ilo = (t - 2 > 0) ? t - 2 : 0;
        int ihi = (t < 12) ? t : 12;
        for (int c = 0; c < 2; ++c)
            for (int i = ilo; i <= ihi; ++i)
                acc += D3W[c * 6 + o * 3 + (t - i)] * usb[c * 13 + i];
        dc3[tid] = tanh_fast(acc);
    }
    __syncthreads();

    // ---- dec4 convT (14,6,3) pad=1: (14,15) -> (6,15); out = flat[2:] ----
    if (tid < 88) {
        int g = tid + 2;
        int o = g / 15, t = g % 15;
        float acc = D4B[o];
        int ilo = (t - 1 > 0) ? t - 1 : 0;
        int ihi = (t + 1 < 14) ? t + 1 : 14;
        for (int c = 0; c < 14; ++c) {
            const float* src = (c < 2) ? (dc3 + c * 15) : (jcat + (c - 2) * 15);
            for (int i = ilo; i <= ihi; ++i)
                acc += D4W[c * 18 + o * 3 + (t - i + 1)] * src[i];
        }
        out[tid] = acc;
    }
}

extern "C" void kernel_launch(void* const* d_in, const int* in_sizes, int n_in,
                              void* d_out, int out_size, void* d_ws, size_t ws_size,
                              hipStream_t stream) {
    const float* x   = (const float*)d_in[0];
    const float* w1  = (const float*)d_in[1];
    const float* b1  = (const float*)d_in[2];
    const float* w2  = (const float*)d_in[3];
    const float* b2  = (const float*)d_in[4];
    const float* w3  = (const float*)d_in[5];
    const float* b3  = (const float*)d_in[6];
    const float* e1w = (const float*)d_in[7];
    const float* e1b = (const float*)d_in[8];
    const float* e2w = (const float*)d_in[9];
    const float* e2b = (const float*)d_in[10];
    const float* d1w = (const float*)d_in[11];
    const float* d1b = (const float*)d_in[12];
    const float* d2w = (const float*)d_in[13];
    const float* d2b = (const float*)d_in[14];
    const float* d3w = (const float*)d_in[15];
    const float* d3b = (const float*)d_in[16];
    const float* d4w = (const float*)d_in[17];
    const float* d4b = (const float*)d_in[18];
    float* out = (float*)d_out;

    convpolicy_kernel<<<1, 256, 0, stream>>>(
        x, w1, b1, w2, b2, w3, b3, e1w, e1b, e2w, e2b,
        d1w, d1b, d2w, d2b, d3w, d3b, d4w, d4b, out);
}